// Round 5
// baseline (423.314 us; speedup 1.0000x reference)
//
#include <hip/hip_runtime.h>

// SSIM loss, two-pass separable conv through LDS. 96 planes of 512x512.
// R8/R9: R6 geometry (64x32 tile, 4 blocks/CU) + R5 register policy (4,4).
// (R8 bench lost to infra failure — identical resubmit.)
//
// R6 post-mortem: occupancy recovered (42->84%) but waves_per_eu(8,8)
// forced a 64-VGPR budget; allocator over-shrank to 32 VGPRs and spilled
// to scratch: WRITE_SIZE 192KB -> 134MB, FETCH +67MB, VALUBusy pinned at
// 32% by spill-reload chains. dur 265us.
// Fix: waves_per_eu(4,4) (128-VGPR budget). Measured pressure of this
// structure is ~45-52 (R5: 52 regs, zero spill, RPT1=8; R6 holds fewer
// live accs) -> expect <=64 VGPRs, so runtime still gets 8 waves/EU and
// LDS still gives 4 blocks/CU x 8 waves = 32 waves/CU.
//
// Geometry (unchanged from R6):
//  * Pass 1: vertical conv global->LDS. unit = (col, 4-row seg),
//    74x8 = 592 units; lane-per-column -> coalesced global reads.
//  * h buffer [32][stride 75] float4 {convV(s),convV(d),convV(s2),convV(d2)};
//    odd stride -> conflict-free b128 reads and writes.
//  * Pass 2: thread = (row = tid&31, 4-col seg = tid>>5); 14 contiguous
//    b128 reads, full horizontal reuse; SSIM formula; block reduce.

typedef float v2f __attribute__((ext_vector_type(2)));
typedef float v4f __attribute__((ext_vector_type(4)));

#define IMG 512
#define TW 64               // tile width  (output cols)
#define TH 32               // tile height (output rows)
#define HALO 5
#define HCOLS 74            // TW + 2*HALO columns of h
#define HSTRIDE 75          // in float4 units; odd -> conflict-free
#define RPT1 4              // pass-1 output rows per unit
#define SEGS 8              // TH / RPT1
#define NPIX 25165824.0     // 32*3*512*512

// Gaussian(sigma=1.5, 11 taps), normalized, fp32 (verified R1-R7)
__device__ constexpr float WT[11] = {
    0.00102838f, 0.00759876f, 0.03600077f, 0.10936068f, 0.21300552f,
    0.26601173f,
    0.21300552f, 0.10936068f, 0.03600077f, 0.00759876f, 0.00102838f};

__global__ __launch_bounds__(512)
__attribute__((amdgpu_waves_per_eu(4, 4)))
void ssim_main(const float* __restrict__ clean,
               const float* __restrict__ adv,
               double* __restrict__ accum)
{
    // h[row][col]: float4 {convV(s), convV(d), convV(s^2), convV(d^2)}
    __shared__ __align__(16) v4f hbuf[TH * HSTRIDE];   // 38,400 B
    __shared__ float wpart[8];

    const int tid = threadIdx.x;
    const int b = blockIdx.x;
    const int plane = b >> 7;         // 128 tiles per plane
    const int t7 = b & 127;
    const int tile_x = (t7 & 7) * TW;     // 8 tiles across
    const int tile_y = (t7 >> 3) * TH;    // 16 tiles down

    const float* __restrict__ cp = clean + (size_t)plane * (IMG * IMG);
    const float* __restrict__ ap = adv   + (size_t)plane * (IMG * IMG);

    // ---- Pass 1: vertical conv, global -> LDS ----
    for (int u = tid; u < HCOLS * SEGS; u += 512) {
        const int seg = u / HCOLS;
        const int uc  = u - seg * HCOLS;
        const int col = tile_x + uc - HALO;
        const bool cvalid = ((unsigned)col < IMG);
        const int or0 = seg * RPT1;           // first output row (tile coords)

        v2f accA[RPT1], accB[RPT1];
        #pragma unroll
        for (int o = 0; o < RPT1; ++o) {
            accA[o] = (v2f){0.f, 0.f};
            accB[o] = (v2f){0.f, 0.f};
        }

        #pragma unroll
        for (int j = 0; j < RPT1 + 10; ++j) {
            const int gr = tile_y + or0 - HALO + j;
            v2f t = {0.f, 0.f};
            if (cvalid && (unsigned)gr < IMG) {
                const int gi = gr * IMG + col;
                const float x = cp[gi];
                const float y = ap[gi];
                t.x = x + y;                  // s
                t.y = x - y;                  // d
            }
            const v2f p = t * t;              // {s^2, d^2}
            #pragma unroll
            for (int o = 0; o < RPT1; ++o) {
                const int kv = j - o;
                if (kv >= 0 && kv < 11) {
                    const float w = WT[kv];
                    accA[o] += w * t;
                    accB[o] += w * p;
                }
            }
        }

        #pragma unroll
        for (int o = 0; o < RPT1; ++o) {
            hbuf[(or0 + o) * HSTRIDE + uc] =
                (v4f){accA[o].x, accA[o].y, accB[o].x, accB[o].y};
        }
    }
    __syncthreads();

    // ---- Pass 2: horizontal conv, LDS -> regs, + SSIM + reduce ----
    const int row = tid & 31;
    const int cs  = tid >> 5;                 // 0..15
    const int c0  = cs * 4;                   // output cols c0..c0+3
    const v4f* __restrict__ hrow = hbuf + row * HSTRIDE + c0;

    v2f A[4], B[4];
    #pragma unroll
    for (int o = 0; o < 4; ++o) {
        A[o] = (v2f){0.f, 0.f};
        B[o] = (v2f){0.f, 0.f};
    }

    #pragma unroll
    for (int k = 0; k < 14; ++k) {            // h cols c0+k, k=0..13
        const v4f h = hrow[k];
        const v2f hA = {h.x, h.y};
        const v2f hB = {h.z, h.w};
        #pragma unroll
        for (int o = 0; o < 4; ++o) {
            const int kh = k - o;
            if (kh >= 0 && kh < 11) {
                const float w = WT[kh];
                A[o] += w * hA;
                B[o] += w * hB;
            }
        }
    }

    // u=conv2(s), v=conv2(d), P=conv2(s^2), Q=conv2(d^2), U=u^2, V=v^2:
    //   2*mu12        = (U-V)/2        mu1^2+mu2^2  = (U+V)/2
    //   2*sigma12     = (P-Q)/2-(U-V)/2
    //   sig1^2+sig2^2 = (P+Q)/2-(U+V)/2
    const float C1 = 1e-4f;   // 0.01^2
    const float C2 = 9e-4f;   // 0.03^2
    float lsum = 0.f;
    #pragma unroll
    for (int o = 0; o < 4; ++o) {
        const float U = A[o].x * A[o].x;
        const float V = A[o].y * A[o].y;
        const float halfUmV = 0.5f * (U - V);
        const float halfUpV = 0.5f * (U + V);
        const float num1 = halfUmV + C1;
        const float num2 = 0.5f * (B[o].x - B[o].y) - halfUmV + C2;
        const float den1 = halfUpV + C1;
        const float den2 = 0.5f * (B[o].x + B[o].y) - halfUpV + C2;
        lsum += (num1 * num2) * __builtin_amdgcn_rcpf(den1 * den2);
    }

    // ---- Reduce: wave shuffle -> LDS -> one atomic per block ----
    #pragma unroll
    for (int off = 32; off > 0; off >>= 1)
        lsum += __shfl_down(lsum, off);
    const int lane = tid & 63;
    const int wave = tid >> 6;                // 0..7
    if (lane == 0) wpart[wave] = lsum;
    __syncthreads();
    if (tid == 0) {
        float bs = 0.f;
        #pragma unroll
        for (int w = 0; w < 8; ++w) bs += wpart[w];
        atomicAdd(accum, (double)bs);
    }
}

__global__ void ssim_finalize(const double* __restrict__ accum,
                              float* __restrict__ out)
{
    if (threadIdx.x == 0) {
        out[0] = 1.f - (float)(accum[0] / NPIX);
    }
}

extern "C" void kernel_launch(void* const* d_in, const int* in_sizes, int n_in,
                              void* d_out, int out_size, void* d_ws, size_t ws_size,
                              hipStream_t stream)
{
    const float* clean = (const float*)d_in[0];
    const float* adv   = (const float*)d_in[1];
    float* out = (float*)d_out;
    double* accum = (double*)d_ws;

    hipMemsetAsync(accum, 0, sizeof(double), stream);

    const int nblocks = 96 * 128;  // 96 planes * (8x16 tiles of 64x32)
    ssim_main<<<nblocks, 512, 0, stream>>>(clean, adv, accum);
    ssim_finalize<<<1, 64, 0, stream>>>(accum, out);
}

// Round 6
// 364.104 us; speedup vs baseline: 1.1626x; 1.1626x over previous
//
#include <hip/hip_runtime.h>

// SSIM loss, two-pass separable conv through LDS. 96 planes of 512x512.
// R10: R6 geometry (64x32 tile) + amdgpu_waves_per_eu(4, 8).
//
// The waves_per_eu saga, triangulated over R7/R9:
//  * (8,8) [R7]: min=8 -> hard 64-VGPR budget -> allocator collapsed to
//    32 regs + scratch spills (WRITE_SIZE 134MB, VALUBusy 32%). 265us.
//  * (4,4) [R9]: clean codegen (52 VGPR, 384B writes) BUT max=4 clamps
//    residency to 4 waves/EU = 2 blocks/CU via the granulated-VGPR
//    descriptor field -> Occupancy 42%, VALUBusy 30%. 288us.
//  * (4,8) [this]: min=4 gives the allocator the 128-reg budget it needs
//    to emit the 52-reg spill-free body; max=8 lets HW schedule what the
//    real resources allow: 52 VGPR <= 64 -> 8 waves/EU, 38.4KB LDS ->
//    4 blocks/CU = 32 waves/CU. R7 proved this geometry reaches 84%
//    occupancy; R9 proved this codegen is spill-free. Compose them.
//
// Geometry (unchanged from R6):
//  * Pass 1: vertical conv global->LDS. unit = (col, 4-row seg),
//    74x8 = 592 units; lane-per-column -> coalesced global reads.
//  * h buffer [32][stride 75] float4 {convV(s),convV(d),convV(s2),convV(d2)};
//    odd stride -> conflict-free b128 reads and writes.
//  * Pass 2: thread = (row = tid&31, 4-col seg = tid>>5); 14 contiguous
//    b128 reads, full horizontal reuse; SSIM formula; block reduce.

typedef float v2f __attribute__((ext_vector_type(2)));
typedef float v4f __attribute__((ext_vector_type(4)));

#define IMG 512
#define TW 64               // tile width  (output cols)
#define TH 32               // tile height (output rows)
#define HALO 5
#define HCOLS 74            // TW + 2*HALO columns of h
#define HSTRIDE 75          // in float4 units; odd -> conflict-free
#define RPT1 4              // pass-1 output rows per unit
#define SEGS 8              // TH / RPT1
#define NPIX 25165824.0     // 32*3*512*512

// Gaussian(sigma=1.5, 11 taps), normalized, fp32 (verified R1-R9)
__device__ constexpr float WT[11] = {
    0.00102838f, 0.00759876f, 0.03600077f, 0.10936068f, 0.21300552f,
    0.26601173f,
    0.21300552f, 0.10936068f, 0.03600077f, 0.00759876f, 0.00102838f};

__global__ __launch_bounds__(512)
__attribute__((amdgpu_waves_per_eu(4, 8)))
void ssim_main(const float* __restrict__ clean,
               const float* __restrict__ adv,
               double* __restrict__ accum)
{
    // h[row][col]: float4 {convV(s), convV(d), convV(s^2), convV(d^2)}
    __shared__ __align__(16) v4f hbuf[TH * HSTRIDE];   // 38,400 B
    __shared__ float wpart[8];

    const int tid = threadIdx.x;
    const int b = blockIdx.x;
    const int plane = b >> 7;         // 128 tiles per plane
    const int t7 = b & 127;
    const int tile_x = (t7 & 7) * TW;     // 8 tiles across
    const int tile_y = (t7 >> 3) * TH;    // 16 tiles down

    const float* __restrict__ cp = clean + (size_t)plane * (IMG * IMG);
    const float* __restrict__ ap = adv   + (size_t)plane * (IMG * IMG);

    // ---- Pass 1: vertical conv, global -> LDS ----
    for (int u = tid; u < HCOLS * SEGS; u += 512) {
        const int seg = u / HCOLS;
        const int uc  = u - seg * HCOLS;
        const int col = tile_x + uc - HALO;
        const bool cvalid = ((unsigned)col < IMG);
        const int or0 = seg * RPT1;           // first output row (tile coords)

        v2f accA[RPT1], accB[RPT1];
        #pragma unroll
        for (int o = 0; o < RPT1; ++o) {
            accA[o] = (v2f){0.f, 0.f};
            accB[o] = (v2f){0.f, 0.f};
        }

        #pragma unroll
        for (int j = 0; j < RPT1 + 10; ++j) {
            const int gr = tile_y + or0 - HALO + j;
            v2f t = {0.f, 0.f};
            if (cvalid && (unsigned)gr < IMG) {
                const int gi = gr * IMG + col;
                const float x = cp[gi];
                const float y = ap[gi];
                t.x = x + y;                  // s
                t.y = x - y;                  // d
            }
            const v2f p = t * t;              // {s^2, d^2}
            #pragma unroll
            for (int o = 0; o < RPT1; ++o) {
                const int kv = j - o;
                if (kv >= 0 && kv < 11) {
                    const float w = WT[kv];
                    accA[o] += w * t;
                    accB[o] += w * p;
                }
            }
        }

        #pragma unroll
        for (int o = 0; o < RPT1; ++o) {
            hbuf[(or0 + o) * HSTRIDE + uc] =
                (v4f){accA[o].x, accA[o].y, accB[o].x, accB[o].y};
        }
    }
    __syncthreads();

    // ---- Pass 2: horizontal conv, LDS -> regs, + SSIM + reduce ----
    const int row = tid & 31;
    const int cs  = tid >> 5;                 // 0..15
    const int c0  = cs * 4;                   // output cols c0..c0+3
    const v4f* __restrict__ hrow = hbuf + row * HSTRIDE + c0;

    v2f A[4], B[4];
    #pragma unroll
    for (int o = 0; o < 4; ++o) {
        A[o] = (v2f){0.f, 0.f};
        B[o] = (v2f){0.f, 0.f};
    }

    #pragma unroll
    for (int k = 0; k < 14; ++k) {            // h cols c0+k, k=0..13
        const v4f h = hrow[k];
        const v2f hA = {h.x, h.y};
        const v2f hB = {h.z, h.w};
        #pragma unroll
        for (int o = 0; o < 4; ++o) {
            const int kh = k - o;
            if (kh >= 0 && kh < 11) {
                const float w = WT[kh];
                A[o] += w * hA;
                B[o] += w * hB;
            }
        }
    }

    // u=conv2(s), v=conv2(d), P=conv2(s^2), Q=conv2(d^2), U=u^2, V=v^2:
    //   2*mu12        = (U-V)/2        mu1^2+mu2^2  = (U+V)/2
    //   2*sigma12     = (P-Q)/2-(U-V)/2
    //   sig1^2+sig2^2 = (P+Q)/2-(U+V)/2
    const float C1 = 1e-4f;   // 0.01^2
    const float C2 = 9e-4f;   // 0.03^2
    float lsum = 0.f;
    #pragma unroll
    for (int o = 0; o < 4; ++o) {
        const float U = A[o].x * A[o].x;
        const float V = A[o].y * A[o].y;
        const float halfUmV = 0.5f * (U - V);
        const float halfUpV = 0.5f * (U + V);
        const float num1 = halfUmV + C1;
        const float num2 = 0.5f * (B[o].x - B[o].y) - halfUmV + C2;
        const float den1 = halfUpV + C1;
        const float den2 = 0.5f * (B[o].x + B[o].y) - halfUpV + C2;
        lsum += (num1 * num2) * __builtin_amdgcn_rcpf(den1 * den2);
    }

    // ---- Reduce: wave shuffle -> LDS -> one atomic per block ----
    #pragma unroll
    for (int off = 32; off > 0; off >>= 1)
        lsum += __shfl_down(lsum, off);
    const int lane = tid & 63;
    const int wave = tid >> 6;                // 0..7
    if (lane == 0) wpart[wave] = lsum;
    __syncthreads();
    if (tid == 0) {
        float bs = 0.f;
        #pragma unroll
        for (int w = 0; w < 8; ++w) bs += wpart[w];
        atomicAdd(accum, (double)bs);
    }
}

__global__ void ssim_finalize(const double* __restrict__ accum,
                              float* __restrict__ out)
{
    if (threadIdx.x == 0) {
        out[0] = 1.f - (float)(accum[0] / NPIX);
    }
}

extern "C" void kernel_launch(void* const* d_in, const int* in_sizes, int n_in,
                              void* d_out, int out_size, void* d_ws, size_t ws_size,
                              hipStream_t stream)
{
    const float* clean = (const float*)d_in[0];
    const float* adv   = (const float*)d_in[1];
    float* out = (float*)d_out;
    double* accum = (double*)d_ws;

    hipMemsetAsync(accum, 0, sizeof(double), stream);

    const int nblocks = 96 * 128;  // 96 planes * (8x16 tiles of 64x32)
    ssim_main<<<nblocks, 512, 0, stream>>>(clean, adv, accum);
    ssim_finalize<<<1, 64, 0, stream>>>(accum, out);
}